// Round 2
// baseline (342.008 us; speedup 1.0000x reference)
//
#include <hip/hip_runtime.h>

#define NN 100000   // nodes
#define NE 800000   // edges  (NE % 256 == 0)
#define NG 256      // graphs
#define CH 96       // in/hidden channels
#define OC 16       // out channels
#define NBLK 391    // ceil(NN/256)
#define TM 128      // gemm node tile (8 row-tiles of 16)
#define GBLK 782    // ceil(NN/TM)
#define ABLK 4688   // ceil(NN*12/256)

typedef __attribute__((ext_vector_type(8))) short bf16x8;
typedef __attribute__((ext_vector_type(4))) float f32x4;

// ---------------- bf16 helpers ----------------
__device__ __forceinline__ unsigned short f2bf(float x) {
    unsigned u = __float_as_uint(x);
    return (unsigned short)((u + 0x7fffu + ((u >> 16) & 1u)) >> 16);  // RNE
}
__device__ __forceinline__ float bf2f(unsigned short h) {
    return __uint_as_float(((unsigned)h) << 16);
}
__device__ __forceinline__ void split8(const float4 a, const float4 b,
                                       bf16x8& hi, bf16x8& lo) {
    float v[8] = {a.x, a.y, a.z, a.w, b.x, b.y, b.z, b.w};
#pragma unroll
    for (int j = 0; j < 8; j++) {
        unsigned short h = f2bf(v[j]);
        hi[j] = (short)h;
        lo[j] = (short)f2bf(v[j] - bf2f(h));
    }
}
// 4 packed bf16 pairs (uint4) -> 8 floats
__device__ __forceinline__ void unpack8(uint4 v, float* f) {
    f[0] = __uint_as_float(v.x << 16); f[1] = __uint_as_float(v.x & 0xffff0000u);
    f[2] = __uint_as_float(v.y << 16); f[3] = __uint_as_float(v.y & 0xffff0000u);
    f[4] = __uint_as_float(v.z << 16); f[5] = __uint_as_float(v.z & 0xffff0000u);
    f[6] = __uint_as_float(v.w << 16); f[7] = __uint_as_float(v.w & 0xffff0000u);
}

// ---------------- init: zero cnt/gtot/fb + prep all 3 W -> transposed bf16 hi/lo ----
__global__ __launch_bounds__(256) void k_init(int* __restrict__ cnt,
                                              const float* __restrict__ W1,
                                              const float* __restrict__ W2,
                                              const float* __restrict__ W3,
                                              unsigned short* __restrict__ WH,
                                              unsigned short* __restrict__ WL,
                                              float* __restrict__ fb) {
    int id = blockIdx.x * 256 + threadIdx.x;
    if (id < NN + 4) cnt[id] = 0;  // cnt + gtot slot
    if (id < NG * CH) fb[id] = 0.0f;  // pooled fallback accumulator
    if (id < 3 * CH * CH) {
        int w = id / (CH * CH);
        int r = id - w * (CH * CH);
        int k = r / CH;
        int n = r - k * CH;
        const float* Ws = (w == 0) ? W1 : (w == 1) ? W2 : W3;
        float v = Ws[k * CH + n];
        unsigned short h = f2bf(v);
        WH[w * CH * CH + n * CH + k] = h;
        WL[w * CH * CH + n * CH + k] = f2bf(v - bf2f(h));
    }
}

// ---------------- front: gemm-1 (blocks < GBLK) + edge histogram (rest) --------
// R1 lesson: atomics are MALL-throughput-bound (4x batching regressed); 1 edge/
// thread + gemm-first dispatch order is the proven-fastest configuration.
__global__ __launch_bounds__(256) void k_front(const float* __restrict__ X,
                                               const unsigned short* __restrict__ WH,
                                               const unsigned short* __restrict__ WL,
                                               unsigned short* __restrict__ H,
                                               const int* __restrict__ dst,
                                               int* __restrict__ cnt,
                                               int* __restrict__ slot) {
    __shared__ __align__(16) unsigned short WsH[CH * CH];  // 18 KB
    __shared__ __align__(16) unsigned short WsL[CH * CH];  // 18 KB

    const int tid = threadIdx.x;

    if (blockIdx.x >= GBLK) {  // ---- histogram path ----
        int e = (blockIdx.x - GBLK) * 256 + tid;
        slot[e] = atomicAdd(&cnt[dst[e]], 1);
        return;
    }

    // ---- gemm-1 path: H = X(fp32) @ W1, split-bf16 (3 MFMAs) ----
    const int n0 = blockIdx.x * TM;
    {
        const uint4* sH = reinterpret_cast<const uint4*>(WH);
        const uint4* sL = reinterpret_cast<const uint4*>(WL);
        uint4* dH = reinterpret_cast<uint4*>(WsH);
        uint4* dL = reinterpret_cast<uint4*>(WsL);
        for (int i = tid; i < CH * CH / 8; i += 256) {
            dH[i] = sH[i];
            dL[i] = sL[i];
        }
    }
    __syncthreads();

    const int lane = tid & 63;
    const int wave = tid >> 6;
    const int lrow = lane & 15;
    const int quad = lane >> 4;

    const float4* X4 = reinterpret_cast<const float4*>(X);

    f32x4 acc[2][6];
#pragma unroll
    for (int rt = 0; rt < 2; rt++)
#pragma unroll
        for (int ct = 0; ct < 6; ct++) acc[rt][ct] = (f32x4){0.f, 0.f, 0.f, 0.f};

    int arow[2];
#pragma unroll
    for (int rt = 0; rt < 2; rt++)
        arow[rt] = min(n0 + (wave * 2 + rt) * 16 + lrow, NN - 1);

#pragma unroll
    for (int kc = 0; kc < 3; kc++) {
        bf16x8 ahi[2], alo[2];
#pragma unroll
        for (int rt = 0; rt < 2; rt++) {
            int fo = (arow[rt] * CH + kc * 32 + quad * 8) >> 2;
            split8(X4[fo], X4[fo + 1], ahi[rt], alo[rt]);
        }
#pragma unroll
        for (int ct = 0; ct < 6; ct++) {
            int bo = (ct * 16 + lrow) * CH + kc * 32 + quad * 8;
            bf16x8 bhi = *reinterpret_cast<const bf16x8*>(&WsH[bo]);
            bf16x8 blo = *reinterpret_cast<const bf16x8*>(&WsL[bo]);
#pragma unroll
            for (int rt = 0; rt < 2; rt++) {
                acc[rt][ct] = __builtin_amdgcn_mfma_f32_16x16x32_bf16(
                    alo[rt], bhi, acc[rt][ct], 0, 0, 0);
                acc[rt][ct] = __builtin_amdgcn_mfma_f32_16x16x32_bf16(
                    ahi[rt], blo, acc[rt][ct], 0, 0, 0);
                acc[rt][ct] = __builtin_amdgcn_mfma_f32_16x16x32_bf16(
                    ahi[rt], bhi, acc[rt][ct], 0, 0, 0);
            }
        }
    }

#pragma unroll
    for (int rt = 0; rt < 2; rt++) {
        int rbase = n0 + (wave * 2 + rt) * 16 + quad * 4;
#pragma unroll
        for (int ct = 0; ct < 6; ct++) {
            int col = ct * 16 + lrow;
#pragma unroll
            for (int r = 0; r < 4; r++) {
                int row = rbase + r;
                if (row < NN) H[(size_t)row * CH + col] = f2bf(acc[rt][ct][r]);
            }
        }
    }
}

// unordered CSR offsets: wave-scan + ONE atomic per wave (G12) + dinv + goff
__global__ __launch_bounds__(256) void k_offsets(const int* __restrict__ cnt,
                                                 int* __restrict__ gtot,
                                                 int* __restrict__ off,
                                                 float* __restrict__ dinv,
                                                 const int* __restrict__ batch,
                                                 int* __restrict__ goff) {
    int i = blockIdx.x * 256 + threadIdx.x;
    int lane = threadIdx.x & 63;
    int c = (i < NN) ? cnt[i] : 0;

    // 64-lane inclusive scan
    int incl = c;
#pragma unroll
    for (int d = 1; d < 64; d <<= 1) {
        int t = __shfl_up(incl, d);
        if (lane >= d) incl += t;
    }
    int total = __shfl(incl, 63);
    int base = 0;
    if (lane == 63) base = atomicAdd(gtot, total);
    base = __shfl(base, 63);

    if (i >= NN) return;
    off[i] = base + incl - c;
    dinv[i] = rsqrtf((float)c + 1.0f);
    int b = batch[i];
    int bp = (i > 0) ? batch[i - 1] : -1;
    for (int g = bp + 1; g <= b; g++) goff[g] = i;
    if (i == NN - 1)
        for (int g = b + 1; g <= NG; g++) goff[g] = NN;
}

__global__ __launch_bounds__(256) void k_build(const int* __restrict__ src,
                                               const int* __restrict__ dst,
                                               const int* __restrict__ off,
                                               const int* __restrict__ slot,
                                               const float* __restrict__ dinv,
                                               float2* __restrict__ packed) {
    int e = blockIdx.x * 256 + threadIdx.x;
    int s = src[e];
    int d = dst[e];
    packed[off[d] + slot[e]] = make_float2(__int_as_float(s), dinv[s] * dinv[d]);
}

// ---------------- MFMA GEMM (layers 2,3): H(bf16) = X(bf16) @ W, LDS-staged W ---
__global__ __launch_bounds__(256) void k_gemm_bf16(const unsigned short* __restrict__ X,
                                                   const unsigned short* __restrict__ WH,
                                                   const unsigned short* __restrict__ WL,
                                                   unsigned short* __restrict__ H) {
    __shared__ __align__(16) unsigned short WsH[CH * CH];
    __shared__ __align__(16) unsigned short WsL[CH * CH];

    const int tid = threadIdx.x;
    const int n0 = blockIdx.x * TM;

    {
        const uint4* sH = reinterpret_cast<const uint4*>(WH);
        const uint4* sL = reinterpret_cast<const uint4*>(WL);
        uint4* dH = reinterpret_cast<uint4*>(WsH);
        uint4* dL = reinterpret_cast<uint4*>(WsL);
        for (int i = tid; i < CH * CH / 8; i += 256) {
            dH[i] = sH[i];
            dL[i] = sL[i];
        }
    }
    __syncthreads();

    const int lane = tid & 63;
    const int wave = tid >> 6;
    const int lrow = lane & 15;
    const int quad = lane >> 4;

    f32x4 acc[2][6];
#pragma unroll
    for (int rt = 0; rt < 2; rt++)
#pragma unroll
        for (int ct = 0; ct < 6; ct++) acc[rt][ct] = (f32x4){0.f, 0.f, 0.f, 0.f};

    int arow[2];
#pragma unroll
    for (int rt = 0; rt < 2; rt++)
        arow[rt] = min(n0 + (wave * 2 + rt) * 16 + lrow, NN - 1);

#pragma unroll
    for (int kc = 0; kc < 3; kc++) {
        bf16x8 ahi[2];
#pragma unroll
        for (int rt = 0; rt < 2; rt++)
            ahi[rt] = *reinterpret_cast<const bf16x8*>(
                &X[(size_t)arow[rt] * CH + kc * 32 + quad * 8]);
#pragma unroll
        for (int ct = 0; ct < 6; ct++) {
            int bo = (ct * 16 + lrow) * CH + kc * 32 + quad * 8;
            bf16x8 bhi = *reinterpret_cast<const bf16x8*>(&WsH[bo]);
            bf16x8 blo = *reinterpret_cast<const bf16x8*>(&WsL[bo]);
#pragma unroll
            for (int rt = 0; rt < 2; rt++) {
                acc[rt][ct] = __builtin_amdgcn_mfma_f32_16x16x32_bf16(
                    ahi[rt], blo, acc[rt][ct], 0, 0, 0);
                acc[rt][ct] = __builtin_amdgcn_mfma_f32_16x16x32_bf16(
                    ahi[rt], bhi, acc[rt][ct], 0, 0, 0);
            }
        }
    }

#pragma unroll
    for (int rt = 0; rt < 2; rt++) {
        int rbase = n0 + (wave * 2 + rt) * 16 + quad * 4;
#pragma unroll
        for (int ct = 0; ct < 6; ct++) {
            int col = ct * 16 + lrow;
#pragma unroll
            for (int r = 0; r < 4; r++) {
                int row = rbase + r;
                if (row < NN) H[(size_t)row * CH + col] = f2bf(acc[rt][ct][r]);
            }
        }
    }
}

// ---------------- per-dst aggregation (layers 1,2): 12 threads/node, 4-deep gathers
// (R11-proven depth; deeper/rotated measured neutral -> MSHR-bound)
template <bool RELU>
__global__ __launch_bounds__(256) void k_aggregate(const int* __restrict__ off,
                                                   const int* __restrict__ cnt,
                                                   const float2* __restrict__ packed,
                                                   const float* __restrict__ dinv,
                                                   const float* __restrict__ bias,
                                                   const unsigned short* __restrict__ H,
                                                   unsigned short* __restrict__ Bout) {
    int idx = blockIdx.x * 256 + threadIdx.x;  // NN*12
    if (idx >= NN * 12) return;
    int n = idx / 12;
    int c8 = idx - n * 12;  // 8 channels per thread
    int e0 = off[n];
    int e1 = e0 + cnt[n];

    const uint4* H8 = reinterpret_cast<const uint4*>(H);

    float a[8];
    {
        float hf[8];
        unpack8(H8[(size_t)n * 12 + c8], hf);
        float di = dinv[n];
        float d2 = di * di;
        const float4* bias4 = reinterpret_cast<const float4*>(bias);
        float4 b0 = bias4[c8 * 2], b1 = bias4[c8 * 2 + 1];
        float bf[8] = {b0.x, b0.y, b0.z, b0.w, b1.x, b1.y, b1.z, b1.w};
#pragma unroll
        for (int j = 0; j < 8; j++) a[j] = hf[j] * d2 + bf[j];
    }

    int e = e0;
    for (; e + 4 <= e1; e += 4) {  // 4 outstanding 16B gathers
        float2 p0 = packed[e + 0];
        float2 p1 = packed[e + 1];
        float2 p2 = packed[e + 2];
        float2 p3 = packed[e + 3];
        uint4 v0 = H8[(size_t)__float_as_int(p0.x) * 12 + c8];
        uint4 v1 = H8[(size_t)__float_as_int(p1.x) * 12 + c8];
        uint4 v2 = H8[(size_t)__float_as_int(p2.x) * 12 + c8];
        uint4 v3 = H8[(size_t)__float_as_int(p3.x) * 12 + c8];
        float f0[8], f1[8], f2[8], f3[8];
        unpack8(v0, f0); unpack8(v1, f1); unpack8(v2, f2); unpack8(v3, f3);
#pragma unroll
        for (int j = 0; j < 8; j++)
            a[j] += f0[j] * p0.y + f1[j] * p1.y + f2[j] * p2.y + f3[j] * p3.y;
    }
    for (; e < e1; e++) {
        float2 pc = packed[e];
        uint4 v = H8[(size_t)__float_as_int(pc.x) * 12 + c8];
        float f[8];
        unpack8(v, f);
#pragma unroll
        for (int j = 0; j < 8; j++) a[j] += f[j] * pc.y;
    }
    if (RELU) {
#pragma unroll
        for (int j = 0; j < 8; j++) a[j] = fmaxf(a[j], 0.0f);
    }
    uint4 o;
    o.x = (unsigned)f2bf(a[0]) | ((unsigned)f2bf(a[1]) << 16);
    o.y = (unsigned)f2bf(a[2]) | ((unsigned)f2bf(a[3]) << 16);
    o.z = (unsigned)f2bf(a[4]) | ((unsigned)f2bf(a[5]) << 16);
    o.w = (unsigned)f2bf(a[6]) | ((unsigned)f2bf(a[7]) << 16);
    reinterpret_cast<uint4*>(Bout)[(size_t)n * 12 + c8] = o;
}

// ---------------- layer-3 aggregate fused with graph-mean partials ----------------
// batch is sorted and graphs are ~390 nodes, so a block's ~22 nodes span <=2
// graphs: reduce node rows into LDS per-(block,graph) partials (ds_add_f32)
// instead of materializing the 19.2 MB Bb row buffer that pool would re-read.
__global__ __launch_bounds__(256) void k_agg_pool(const int* __restrict__ off,
                                                  const int* __restrict__ cnt,
                                                  const float2* __restrict__ packed,
                                                  const float* __restrict__ dinv,
                                                  const float* __restrict__ bias,
                                                  const unsigned short* __restrict__ H,
                                                  const int* __restrict__ batch,
                                                  float* __restrict__ part,
                                                  int* __restrict__ pgid,
                                                  float* __restrict__ fb) {
    __shared__ float psum[4][CH];  // 1.5 KB
    const int tid = threadIdx.x;
    for (int i = tid; i < 4 * CH; i += 256) (&psum[0][0])[i] = 0.0f;

    const int idx = blockIdx.x * 256 + tid;
    const int n0 = (blockIdx.x * 256) / 12;
    const int g0 = batch[n0];
    __syncthreads();

    if (idx < NN * 12) {  // no early return: barriers below
        int n = idx / 12;
        int c8 = idx - n * 12;
        int e0 = off[n];
        int e1 = e0 + cnt[n];

        const uint4* H8 = reinterpret_cast<const uint4*>(H);

        float a[8];
        {
            float hf[8];
            unpack8(H8[(size_t)n * 12 + c8], hf);
            float di = dinv[n];
            float d2 = di * di;
            const float4* bias4 = reinterpret_cast<const float4*>(bias);
            float4 b0 = bias4[c8 * 2], b1 = bias4[c8 * 2 + 1];
            float bf[8] = {b0.x, b0.y, b0.z, b0.w, b1.x, b1.y, b1.z, b1.w};
#pragma unroll
            for (int j = 0; j < 8; j++) a[j] = hf[j] * d2 + bf[j];
        }

        int e = e0;
        for (; e + 4 <= e1; e += 4) {
            float2 p0 = packed[e + 0];
            float2 p1 = packed[e + 1];
            float2 p2 = packed[e + 2];
            float2 p3 = packed[e + 3];
            uint4 v0 = H8[(size_t)__float_as_int(p0.x) * 12 + c8];
            uint4 v1 = H8[(size_t)__float_as_int(p1.x) * 12 + c8];
            uint4 v2 = H8[(size_t)__float_as_int(p2.x) * 12 + c8];
            uint4 v3 = H8[(size_t)__float_as_int(p3.x) * 12 + c8];
            float f0[8], f1[8], f2[8], f3[8];
            unpack8(v0, f0); unpack8(v1, f1); unpack8(v2, f2); unpack8(v3, f3);
#pragma unroll
            for (int j = 0; j < 8; j++)
                a[j] += f0[j] * p0.y + f1[j] * p1.y + f2[j] * p2.y + f3[j] * p3.y;
        }
        for (; e < e1; e++) {
            float2 pc = packed[e];
            uint4 v = H8[(size_t)__float_as_int(pc.x) * 12 + c8];
            float f[8];
            unpack8(v, f);
#pragma unroll
            for (int j = 0; j < 8; j++) a[j] += f[j] * pc.y;
        }

        int g = batch[n];
        int gi = g - g0;
        if (gi < 4) {
#pragma unroll
            for (int j = 0; j < 8; j++) atomicAdd(&psum[gi][c8 * 8 + j], a[j]);
        } else {  // distributionally impossible (needs a <12-node graph); correctness net
#pragma unroll
            for (int j = 0; j < 8; j++) atomicAdd(&fb[g * CH + c8 * 8 + j], a[j]);
        }
    }
    __syncthreads();

    for (int i = tid; i < 4 * CH; i += 256)
        part[(size_t)blockIdx.x * (4 * CH) + i] = (&psum[0][0])[i];
    if (tid < 4) pgid[blockIdx.x * 4 + tid] = g0 + tid;
}

// ---------------- per-graph partial reduction + final linear (fp32 end-to-end) ----
__global__ __launch_bounds__(128) void k_pool2(const int* __restrict__ goff,
                                               const float* __restrict__ part,
                                               const int* __restrict__ pgid,
                                               const float* __restrict__ fb,
                                               const float* __restrict__ Wlin,
                                               float* __restrict__ out) {
    __shared__ float pooled[CH];
    int g = blockIdx.x;
    int t = threadIdx.x;
    int s = goff[g];
    int e = goff[g + 1];

    if (t < CH) {
        float acc = fb[g * CH + t];
        if (e > s) {
            int blo = (12 * s) / 256;
            int bhi = (12 * (e - 1) + 11) / 256;
            if (bhi > ABLK - 1) bhi = ABLK - 1;
            for (int b = blo; b <= bhi; b++) {
#pragma unroll
                for (int sl = 0; sl < 4; sl++)
                    if (pgid[b * 4 + sl] == g)
                        acc += part[(size_t)b * (4 * CH) + sl * CH + t];
            }
        }
        pooled[t] = acc / fmaxf((float)(e - s), 1.0f);
    }
    __syncthreads();

    if (t < OC) {
        float a = 0.0f;
#pragma unroll 8
        for (int k = 0; k < CH; k++) a += pooled[k] * Wlin[k * OC + t];
        out[g * OC + t] = a;
    }
}

// ---------------- launch ----------------
extern "C" void kernel_launch(void* const* d_in, const int* in_sizes, int n_in,
                              void* d_out, int out_size, void* d_ws, size_t ws_size,
                              hipStream_t stream) {
    const float* x = (const float*)d_in[0];
    const int* ei = (const int*)d_in[1];
    const int* src = ei;
    const int* dst = ei + NE;
    const int* batch = (const int*)d_in[2];
    const float* W1 = (const float*)d_in[3];
    const float* b1 = (const float*)d_in[4];
    const float* W2 = (const float*)d_in[5];
    const float* b2 = (const float*)d_in[6];
    const float* W3 = (const float*)d_in[7];
    const float* b3 = (const float*)d_in[8];
    const float* Wlin = (const float*)d_in[9];
    float* out = (float*)d_out;

    char* ws = (char*)d_ws;
    unsigned short* Ha = (unsigned short*)ws;  ws += (size_t)NN * CH * 2;  // 19.2 MB
    unsigned short* Hb = (unsigned short*)ws;  ws += (size_t)NN * CH * 2;  // 19.2 MB
    unsigned short* Bb = (unsigned short*)ws;  ws += (size_t)NN * CH * 2;  // 19.2 MB
    float2* packed = (float2*)ws;   ws += (size_t)NE * 8;        // 6.4 MB
    unsigned short* WH = (unsigned short*)ws;  ws += 3 * CH * CH * 2;  // 55 KB
    unsigned short* WL = (unsigned short*)ws;  ws += 3 * CH * CH * 2;
    float* dinv = (float*)ws;       ws += NN * 4;
    int* off = (int*)ws;            ws += NN * 4;
    int* goff = (int*)ws;           ws += 272 * 4;       // NG+1, padded
    int* cnt = (int*)ws;            ws += (NN + 4) * 4;  // +gtot slot
    int* gtot = cnt + NN;
    float* fb = (float*)ws;         ws += NG * CH * 4;   // 98 KB pooled fallback
    // slot aliases Bb (dead until agg1 writes it; slot last read by k_build).
    // part/pgid also alias Bb (dead after gemm3 reads it; 7.3 MB < 19.2 MB).
    int* slot = (int*)Bb;
    float* part = (float*)Bb;                         // ABLK*384 floats = 7.2 MB
    int* pgid = (int*)((char*)Bb + (size_t)ABLK * 4 * CH * 4);  // +75 KB

    // init (zero cnt/gtot/fb + W prep), front (gemm1 || hist), offsets, build
    k_init<<<NBLK, 256, 0, stream>>>(cnt, W1, W2, W3, WH, WL, fb);
    k_front<<<GBLK + NE / 256, 256, 0, stream>>>(x, WH, WL, Ha, dst, cnt, slot);
    k_offsets<<<NBLK, 256, 0, stream>>>(cnt, gtot, off, dinv, batch, goff);
    k_build<<<NE / 256, 256, 0, stream>>>(src, dst, off, slot, dinv, packed);

    // layer 1 aggregate: Ha -> Bb (relu)
    k_aggregate<true><<<ABLK, 256, 0, stream>>>(off, cnt, packed, dinv, b1, Ha, Bb);
    // layer 2: Bb -> Hb -> Bb (relu)
    k_gemm_bf16<<<GBLK, 256, 0, stream>>>(Bb, WH + CH * CH, WL + CH * CH, Hb);
    k_aggregate<true><<<ABLK, 256, 0, stream>>>(off, cnt, packed, dinv, b2, Hb, Bb);
    // layer 3: Bb -> Ha; aggregate fused with per-graph partial reduction
    k_gemm_bf16<<<GBLK, 256, 0, stream>>>(Bb, WH + 2 * CH * CH, WL + 2 * CH * CH, Ha);
    k_agg_pool<<<ABLK, 256, 0, stream>>>(off, cnt, packed, dinv, b3, Ha, batch,
                                         part, pgid, fb);

    // per-graph partial sum + final linear
    k_pool2<<<NG, 128, 0, stream>>>(goff, part, pgid, fb, Wlin, out);
}

// Round 3
// 305.102 us; speedup vs baseline: 1.1210x; 1.1210x over previous
//
#include <hip/hip_runtime.h>

#define NN 100000   // nodes
#define NE 800000   // edges  (NE % 256 == 0)
#define NG 256      // graphs
#define CH 96       // in/hidden channels
#define OC 16       // out channels
#define NBLK 391    // ceil(NN/256)
#define TM 128      // gemm node tile (8 row-tiles of 16)
#define GBLK 782    // ceil(NN/TM)

typedef __attribute__((ext_vector_type(8))) short bf16x8;
typedef __attribute__((ext_vector_type(4))) float f32x4;

// ---------------- bf16 helpers ----------------
__device__ __forceinline__ unsigned short f2bf(float x) {
    unsigned u = __float_as_uint(x);
    return (unsigned short)((u + 0x7fffu + ((u >> 16) & 1u)) >> 16);  // RNE
}
__device__ __forceinline__ float bf2f(unsigned short h) {
    return __uint_as_float(((unsigned)h) << 16);
}
__device__ __forceinline__ void split8(const float4 a, const float4 b,
                                       bf16x8& hi, bf16x8& lo) {
    float v[8] = {a.x, a.y, a.z, a.w, b.x, b.y, b.z, b.w};
#pragma unroll
    for (int j = 0; j < 8; j++) {
        unsigned short h = f2bf(v[j]);
        hi[j] = (short)h;
        lo[j] = (short)f2bf(v[j] - bf2f(h));
    }
}
__device__ __forceinline__ float4 us4_to_f4(ushort4 u) {
    return make_float4(bf2f(u.x), bf2f(u.y), bf2f(u.z), bf2f(u.w));
}
// 4 packed bf16 pairs (uint4) -> 8 floats
__device__ __forceinline__ void unpack8(uint4 v, float* f) {
    f[0] = __uint_as_float(v.x << 16); f[1] = __uint_as_float(v.x & 0xffff0000u);
    f[2] = __uint_as_float(v.y << 16); f[3] = __uint_as_float(v.y & 0xffff0000u);
    f[4] = __uint_as_float(v.z << 16); f[5] = __uint_as_float(v.z & 0xffff0000u);
    f[6] = __uint_as_float(v.w << 16); f[7] = __uint_as_float(v.w & 0xffff0000u);
}

// ---------------- init: zero cnt/gtot + prep all 3 W -> transposed bf16 hi/lo ----
__global__ __launch_bounds__(256) void k_init(int* __restrict__ cnt,
                                              const float* __restrict__ W1,
                                              const float* __restrict__ W2,
                                              const float* __restrict__ W3,
                                              unsigned short* __restrict__ WH,
                                              unsigned short* __restrict__ WL) {
    int id = blockIdx.x * 256 + threadIdx.x;
    if (id < NN + 4) cnt[id] = 0;  // cnt + gtot slot
    if (id < 3 * CH * CH) {
        int w = id / (CH * CH);
        int r = id - w * (CH * CH);
        int k = r / CH;
        int n = r - k * CH;
        const float* Ws = (w == 0) ? W1 : (w == 1) ? W2 : W3;
        float v = Ws[k * CH + n];
        unsigned short h = f2bf(v);
        WH[w * CH * CH + n * CH + k] = h;
        WL[w * CH * CH + n * CH + k] = f2bf(v - bf2f(h));
    }
}

// ---------------- front: gemm-1 (blocks < GBLK) + edge histogram (rest) --------
// R3 change: W staged in 96x32 kc-chunks (12 KB LDS vs 36 KB) so BOTH paths
// reside at 8 blocks/CU. Hist is atomic-latency x concurrency bound (20 G/s
// << throughput ceiling, occupancy was 31%): doubling resident hist waves
// doubles in-flight atomics. Gemm path work is identical (+4 cheap barriers).
__global__ __launch_bounds__(256) void k_front(const float* __restrict__ X,
                                               const unsigned short* __restrict__ WH,
                                               const unsigned short* __restrict__ WL,
                                               unsigned short* __restrict__ H,
                                               const int* __restrict__ dst,
                                               int* __restrict__ cnt,
                                               int* __restrict__ slot) {
    __shared__ __align__(16) unsigned short WsH[CH * 32];  // 6 KB (kc chunk)
    __shared__ __align__(16) unsigned short WsL[CH * 32];  // 6 KB

    const int tid = threadIdx.x;

    if (blockIdx.x >= GBLK) {  // ---- histogram path ----
        int e = (blockIdx.x - GBLK) * 256 + tid;
        slot[e] = atomicAdd(&cnt[dst[e]], 1);
        return;
    }

    // ---- gemm-1 path: H = X(fp32) @ W1, split-bf16 (3 MFMAs) ----
    const int n0 = blockIdx.x * TM;

    const int lane = tid & 63;
    const int wave = tid >> 6;
    const int lrow = lane & 15;
    const int quad = lane >> 4;

    const float4* X4 = reinterpret_cast<const float4*>(X);
    const uint4* sH = reinterpret_cast<const uint4*>(WH);
    const uint4* sL = reinterpret_cast<const uint4*>(WL);
    uint4* dH = reinterpret_cast<uint4*>(WsH);
    uint4* dL = reinterpret_cast<uint4*>(WsL);

    f32x4 acc[2][6];
#pragma unroll
    for (int rt = 0; rt < 2; rt++)
#pragma unroll
        for (int ct = 0; ct < 6; ct++) acc[rt][ct] = (f32x4){0.f, 0.f, 0.f, 0.f};

    int arow[2];
#pragma unroll
    for (int rt = 0; rt < 2; rt++)
        arow[rt] = min(n0 + (wave * 2 + rt) * 16 + lrow, NN - 1);

#pragma unroll
    for (int kc = 0; kc < 3; kc++) {
        // stage W chunk: 96 rows x 32 cols (4 uint4 per row)
        if (kc) __syncthreads();
        for (int i = tid; i < CH * 4; i += 256) {
            int row = i >> 2, c4 = i & 3;
            dH[i] = sH[row * (CH / 8) + kc * 4 + c4];
            dL[i] = sL[row * (CH / 8) + kc * 4 + c4];
        }
        __syncthreads();

        bf16x8 ahi[2], alo[2];
#pragma unroll
        for (int rt = 0; rt < 2; rt++) {
            int fo = (arow[rt] * CH + kc * 32 + quad * 8) >> 2;
            split8(X4[fo], X4[fo + 1], ahi[rt], alo[rt]);
        }
#pragma unroll
        for (int ct = 0; ct < 6; ct++) {
            int bo = (ct * 16 + lrow) * 32 + quad * 8;
            bf16x8 bhi = *reinterpret_cast<const bf16x8*>(&WsH[bo]);
            bf16x8 blo = *reinterpret_cast<const bf16x8*>(&WsL[bo]);
#pragma unroll
            for (int rt = 0; rt < 2; rt++) {
                acc[rt][ct] = __builtin_amdgcn_mfma_f32_16x16x32_bf16(
                    alo[rt], bhi, acc[rt][ct], 0, 0, 0);
                acc[rt][ct] = __builtin_amdgcn_mfma_f32_16x16x32_bf16(
                    ahi[rt], blo, acc[rt][ct], 0, 0, 0);
                acc[rt][ct] = __builtin_amdgcn_mfma_f32_16x16x32_bf16(
                    ahi[rt], bhi, acc[rt][ct], 0, 0, 0);
            }
        }
    }

#pragma unroll
    for (int rt = 0; rt < 2; rt++) {
        int rbase = n0 + (wave * 2 + rt) * 16 + quad * 4;
#pragma unroll
        for (int ct = 0; ct < 6; ct++) {
            int col = ct * 16 + lrow;
#pragma unroll
            for (int r = 0; r < 4; r++) {
                int row = rbase + r;
                if (row < NN) H[(size_t)row * CH + col] = f2bf(acc[rt][ct][r]);
            }
        }
    }
}

// unordered CSR offsets: wave-scan + ONE atomic per wave (G12) + dinv + goff
__global__ __launch_bounds__(256) void k_offsets(const int* __restrict__ cnt,
                                                 int* __restrict__ gtot,
                                                 int* __restrict__ off,
                                                 float* __restrict__ dinv,
                                                 const int* __restrict__ batch,
                                                 int* __restrict__ goff) {
    int i = blockIdx.x * 256 + threadIdx.x;
    int lane = threadIdx.x & 63;
    int c = (i < NN) ? cnt[i] : 0;

    // 64-lane inclusive scan
    int incl = c;
#pragma unroll
    for (int d = 1; d < 64; d <<= 1) {
        int t = __shfl_up(incl, d);
        if (lane >= d) incl += t;
    }
    int total = __shfl(incl, 63);
    int base = 0;
    if (lane == 63) base = atomicAdd(gtot, total);
    base = __shfl(base, 63);

    if (i >= NN) return;
    off[i] = base + incl - c;
    dinv[i] = rsqrtf((float)c + 1.0f);
    int b = batch[i];
    int bp = (i > 0) ? batch[i - 1] : -1;
    for (int g = bp + 1; g <= b; g++) goff[g] = i;
    if (i == NN - 1)
        for (int g = b + 1; g <= NG; g++) goff[g] = NN;
}

__global__ __launch_bounds__(256) void k_build(const int* __restrict__ src,
                                               const int* __restrict__ dst,
                                               const int* __restrict__ off,
                                               const int* __restrict__ slot,
                                               const float* __restrict__ dinv,
                                               float2* __restrict__ packed) {
    int e = blockIdx.x * 256 + threadIdx.x;
    int s = src[e];
    int d = dst[e];
    packed[off[d] + slot[e]] = make_float2(__int_as_float(s), dinv[s] * dinv[d]);
}

// ---------------- MFMA GEMM (layers 2,3): H(bf16) = X(bf16) @ W, LDS-staged W ---
__global__ __launch_bounds__(256) void k_gemm_bf16(const unsigned short* __restrict__ X,
                                                   const unsigned short* __restrict__ WH,
                                                   const unsigned short* __restrict__ WL,
                                                   unsigned short* __restrict__ H) {
    __shared__ __align__(16) unsigned short WsH[CH * CH];
    __shared__ __align__(16) unsigned short WsL[CH * CH];

    const int tid = threadIdx.x;
    const int n0 = blockIdx.x * TM;

    {
        const uint4* sH = reinterpret_cast<const uint4*>(WH);
        const uint4* sL = reinterpret_cast<const uint4*>(WL);
        uint4* dH = reinterpret_cast<uint4*>(WsH);
        uint4* dL = reinterpret_cast<uint4*>(WsL);
        for (int i = tid; i < CH * CH / 8; i += 256) {
            dH[i] = sH[i];
            dL[i] = sL[i];
        }
    }
    __syncthreads();

    const int lane = tid & 63;
    const int wave = tid >> 6;
    const int lrow = lane & 15;
    const int quad = lane >> 4;

    f32x4 acc[2][6];
#pragma unroll
    for (int rt = 0; rt < 2; rt++)
#pragma unroll
        for (int ct = 0; ct < 6; ct++) acc[rt][ct] = (f32x4){0.f, 0.f, 0.f, 0.f};

    int arow[2];
#pragma unroll
    for (int rt = 0; rt < 2; rt++)
        arow[rt] = min(n0 + (wave * 2 + rt) * 16 + lrow, NN - 1);

#pragma unroll
    for (int kc = 0; kc < 3; kc++) {
        bf16x8 ahi[2];
#pragma unroll
        for (int rt = 0; rt < 2; rt++)
            ahi[rt] = *reinterpret_cast<const bf16x8*>(
                &X[(size_t)arow[rt] * CH + kc * 32 + quad * 8]);
#pragma unroll
        for (int ct = 0; ct < 6; ct++) {
            int bo = (ct * 16 + lrow) * CH + kc * 32 + quad * 8;
            bf16x8 bhi = *reinterpret_cast<const bf16x8*>(&WsH[bo]);
            bf16x8 blo = *reinterpret_cast<const bf16x8*>(&WsL[bo]);
#pragma unroll
            for (int rt = 0; rt < 2; rt++) {
                acc[rt][ct] = __builtin_amdgcn_mfma_f32_16x16x32_bf16(
                    ahi[rt], blo, acc[rt][ct], 0, 0, 0);
                acc[rt][ct] = __builtin_amdgcn_mfma_f32_16x16x32_bf16(
                    ahi[rt], bhi, acc[rt][ct], 0, 0, 0);
            }
        }
    }

#pragma unroll
    for (int rt = 0; rt < 2; rt++) {
        int rbase = n0 + (wave * 2 + rt) * 16 + quad * 4;
#pragma unroll
        for (int ct = 0; ct < 6; ct++) {
            int col = ct * 16 + lrow;
#pragma unroll
            for (int r = 0; r < 4; r++) {
                int row = rbase + r;
                if (row < NN) H[(size_t)row * CH + col] = f2bf(acc[rt][ct][r]);
            }
        }
    }
}

// ---------------- per-dst aggregation: 12 threads/node, 4-deep 16 B gathers ------
// (R11-proven depth; deeper/rotated/LDS-fused all measured worse -> MSHR-bound)
template <bool RELU>
__global__ __launch_bounds__(256) void k_aggregate(const int* __restrict__ off,
                                                   const int* __restrict__ cnt,
                                                   const float2* __restrict__ packed,
                                                   const float* __restrict__ dinv,
                                                   const float* __restrict__ bias,
                                                   const unsigned short* __restrict__ H,
                                                   unsigned short* __restrict__ Bout) {
    int idx = blockIdx.x * 256 + threadIdx.x;  // NN*12
    if (idx >= NN * 12) return;
    int n = idx / 12;
    int c8 = idx - n * 12;  // 8 channels per thread
    int e0 = off[n];
    int e1 = e0 + cnt[n];

    const uint4* H8 = reinterpret_cast<const uint4*>(H);

    float a[8];
    {
        float hf[8];
        unpack8(H8[(size_t)n * 12 + c8], hf);
        float di = dinv[n];
        float d2 = di * di;
        const float4* bias4 = reinterpret_cast<const float4*>(bias);
        float4 b0 = bias4[c8 * 2], b1 = bias4[c8 * 2 + 1];
        float bf[8] = {b0.x, b0.y, b0.z, b0.w, b1.x, b1.y, b1.z, b1.w};
#pragma unroll
        for (int j = 0; j < 8; j++) a[j] = hf[j] * d2 + bf[j];
    }

    int e = e0;
    for (; e + 4 <= e1; e += 4) {  // 4 outstanding 16B gathers
        float2 p0 = packed[e + 0];
        float2 p1 = packed[e + 1];
        float2 p2 = packed[e + 2];
        float2 p3 = packed[e + 3];
        uint4 v0 = H8[(size_t)__float_as_int(p0.x) * 12 + c8];
        uint4 v1 = H8[(size_t)__float_as_int(p1.x) * 12 + c8];
        uint4 v2 = H8[(size_t)__float_as_int(p2.x) * 12 + c8];
        uint4 v3 = H8[(size_t)__float_as_int(p3.x) * 12 + c8];
        float f0[8], f1[8], f2[8], f3[8];
        unpack8(v0, f0); unpack8(v1, f1); unpack8(v2, f2); unpack8(v3, f3);
#pragma unroll
        for (int j = 0; j < 8; j++)
            a[j] += f0[j] * p0.y + f1[j] * p1.y + f2[j] * p2.y + f3[j] * p3.y;
    }
    for (; e < e1; e++) {
        float2 pc = packed[e];
        uint4 v = H8[(size_t)__float_as_int(pc.x) * 12 + c8];
        float f[8];
        unpack8(v, f);
#pragma unroll
        for (int j = 0; j < 8; j++) a[j] += f[j] * pc.y;
    }
    if (RELU) {
#pragma unroll
        for (int j = 0; j < 8; j++) a[j] = fmaxf(a[j], 0.0f);
    }
    uint4 o;
    o.x = (unsigned)f2bf(a[0]) | ((unsigned)f2bf(a[1]) << 16);
    o.y = (unsigned)f2bf(a[2]) | ((unsigned)f2bf(a[3]) << 16);
    o.z = (unsigned)f2bf(a[4]) | ((unsigned)f2bf(a[5]) << 16);
    o.w = (unsigned)f2bf(a[6]) | ((unsigned)f2bf(a[7]) << 16);
    reinterpret_cast<uint4*>(Bout)[(size_t)n * 12 + c8] = o;
}

// ---------------- fused pool + final linear (bf16 input) ----------------
__global__ __launch_bounds__(384) void k_pool_linear(const int* __restrict__ goff,
                                                     const unsigned short* __restrict__ B,
                                                     const float* __restrict__ Wlin,
                                                     float* __restrict__ out) {
    __shared__ float4 sh[16][24];
    __shared__ float pooled[CH];
    int g = blockIdx.x;
    int t = threadIdx.x;
    int nl = t / 24;
    int c4 = t - nl * 24;
    int s = goff[g];
    int e = goff[g + 1];

    float4 acc = make_float4(0.f, 0.f, 0.f, 0.f);
    const ushort4* B4 = reinterpret_cast<const ushort4*>(B);
    for (int n = s + nl; n < e; n += 16) {
        float4 v = us4_to_f4(B4[(size_t)n * 24 + c4]);
        acc.x += v.x; acc.y += v.y; acc.z += v.z; acc.w += v.w;
    }
    sh[nl][c4] = acc;
    __syncthreads();

    if (t < 24) {
        float4 r = make_float4(0.f, 0.f, 0.f, 0.f);
#pragma unroll
        for (int j = 0; j < 16; j++) {
            float4 v = sh[j][t];
            r.x += v.x; r.y += v.y; r.z += v.z; r.w += v.w;
        }
        float inv = 1.0f / fmaxf((float)(e - s), 1.0f);
        pooled[t * 4 + 0] = r.x * inv;
        pooled[t * 4 + 1] = r.y * inv;
        pooled[t * 4 + 2] = r.z * inv;
        pooled[t * 4 + 3] = r.w * inv;
    }
    __syncthreads();

    if (t < OC) {
        float a = 0.0f;
#pragma unroll 8
        for (int k = 0; k < CH; k++) a += pooled[k] * Wlin[k * OC + t];
        out[g * OC + t] = a;
    }
}

// ---------------- launch ----------------
extern "C" void kernel_launch(void* const* d_in, const int* in_sizes, int n_in,
                              void* d_out, int out_size, void* d_ws, size_t ws_size,
                              hipStream_t stream) {
    const float* x = (const float*)d_in[0];
    const int* ei = (const int*)d_in[1];
    const int* src = ei;
    const int* dst = ei + NE;
    const int* batch = (const int*)d_in[2];
    const float* W1 = (const float*)d_in[3];
    const float* b1 = (const float*)d_in[4];
    const float* W2 = (const float*)d_in[5];
    const float* b2 = (const float*)d_in[6];
    const float* W3 = (const float*)d_in[7];
    const float* b3 = (const float*)d_in[8];
    const float* Wlin = (const float*)d_in[9];
    float* out = (float*)d_out;

    char* ws = (char*)d_ws;
    unsigned short* Ha = (unsigned short*)ws;  ws += (size_t)NN * CH * 2;  // 19.2 MB
    unsigned short* Hb = (unsigned short*)ws;  ws += (size_t)NN * CH * 2;  // 19.2 MB
    unsigned short* Bb = (unsigned short*)ws;  ws += (size_t)NN * CH * 2;  // 19.2 MB
    float2* packed = (float2*)ws;   ws += (size_t)NE * 8;        // 6.4 MB
    unsigned short* WH = (unsigned short*)ws;  ws += 3 * CH * CH * 2;  // 55 KB
    unsigned short* WL = (unsigned short*)ws;  ws += 3 * CH * CH * 2;
    float* dinv = (float*)ws;       ws += NN * 4;
    int* off = (int*)ws;            ws += NN * 4;
    int* goff = (int*)ws;           ws += 272 * 4;       // NG+1, padded
    int* cnt = (int*)ws;            ws += (NN + 4) * 4;  // +gtot slot
    int* gtot = cnt + NN;
    int* slot = (int*)Bb;  // Bb dead until agg1 writes it; slot last read by k_build

    // init (zero cnt/gtot + W prep), front (gemm1 || hist), offsets, build
    k_init<<<NBLK, 256, 0, stream>>>(cnt, W1, W2, W3, WH, WL);
    k_front<<<GBLK + NE / 256, 256, 0, stream>>>(x, WH, WL, Ha, dst, cnt, slot);
    k_offsets<<<NBLK, 256, 0, stream>>>(cnt, gtot, off, dinv, batch, goff);
    k_build<<<NE / 256, 256, 0, stream>>>(src, dst, off, slot, dinv, packed);

    const int ablk = (NN * 12 + 255) / 256;

    // layer 1 aggregate: Ha -> Bb (relu)
    k_aggregate<true><<<ablk, 256, 0, stream>>>(off, cnt, packed, dinv, b1, Ha, Bb);
    // layer 2: Bb -> Hb -> Bb (relu)
    k_gemm_bf16<<<GBLK, 256, 0, stream>>>(Bb, WH + CH * CH, WL + CH * CH, Hb);
    k_aggregate<true><<<ablk, 256, 0, stream>>>(off, cnt, packed, dinv, b2, Hb, Bb);
    // layer 3: Bb -> Ha -> Bb (no relu)
    k_gemm_bf16<<<GBLK, 256, 0, stream>>>(Bb, WH + 2 * CH * CH, WL + 2 * CH * CH, Ha);
    k_aggregate<false><<<ablk, 256, 0, stream>>>(off, cnt, packed, dinv, b3, Ha, Bb);

    // fused pool + linear
    k_pool_linear<<<NG, 384, 0, stream>>>(goff, Bb, Wlin, out);
}

// Round 4
// 299.248 us; speedup vs baseline: 1.1429x; 1.0196x over previous
//
#include <hip/hip_runtime.h>

#define NN 100000   // nodes
#define NE 800000   // edges  (NE % 256 == 0)
#define NG 256      // graphs
#define CH 96      // in/hidden channels
#define OC 16       // out channels
#define NBLK 391    // ceil(NN/256)
#define TM 128      // gemm node tile (8 row-tiles of 16)
#define GBLK 782    // ceil(NN/TM)

typedef __attribute__((ext_vector_type(8))) short bf16x8;
typedef __attribute__((ext_vector_type(4))) float f32x4;

// ---------------- bf16 helpers ----------------
__device__ __forceinline__ unsigned short f2bf(float x) {
    unsigned u = __float_as_uint(x);
    return (unsigned short)((u + 0x7fffu + ((u >> 16) & 1u)) >> 16);  // RNE
}
__device__ __forceinline__ float bf2f(unsigned short h) {
    return __uint_as_float(((unsigned)h) << 16);
}
__device__ __forceinline__ void split8(const float4 a, const float4 b,
                                       bf16x8& hi, bf16x8& lo) {
    float v[8] = {a.x, a.y, a.z, a.w, b.x, b.y, b.z, b.w};
#pragma unroll
    for (int j = 0; j < 8; j++) {
        unsigned short h = f2bf(v[j]);
        hi[j] = (short)h;
        lo[j] = (short)f2bf(v[j] - bf2f(h));
    }
}
__device__ __forceinline__ float4 us4_to_f4(ushort4 u) {
    return make_float4(bf2f(u.x), bf2f(u.y), bf2f(u.z), bf2f(u.w));
}
// 4 packed bf16 pairs (uint4) -> 8 floats
__device__ __forceinline__ void unpack8(uint4 v, float* f) {
    f[0] = __uint_as_float(v.x << 16); f[1] = __uint_as_float(v.x & 0xffff0000u);
    f[2] = __uint_as_float(v.y << 16); f[3] = __uint_as_float(v.y & 0xffff0000u);
    f[4] = __uint_as_float(v.z << 16); f[5] = __uint_as_float(v.z & 0xffff0000u);
    f[6] = __uint_as_float(v.w << 16); f[7] = __uint_as_float(v.w & 0xffff0000u);
}

// ---------------- init: zero padded cnt/gtot + prep all 3 W -> transposed bf16 ----
// cnt is padded to ONE COUNTER PER 64B LINE (cnt[i*16]): the hist's 800k RMWs
// previously piled ~128 atomics on each of 6250 lines; same-line RMW turnaround
// at the L2 slice (~4cy) predicts the observed ~40us. Padding spreads to 100k lines.
__global__ __launch_bounds__(256) void k_init(int* __restrict__ cntp,
                                              int* __restrict__ gtot,
                                              const float* __restrict__ W1,
                                              const float* __restrict__ W2,
                                              const float* __restrict__ W3,
                                              unsigned short* __restrict__ WH,
                                              unsigned short* __restrict__ WL) {
    int id = blockIdx.x * 256 + threadIdx.x;
    if (id < NN) {
        uint4 z = {0u, 0u, 0u, 0u};
        uint4* p = reinterpret_cast<uint4*>(&cntp[(size_t)id * 16]);
        p[0] = z; p[1] = z; p[2] = z; p[3] = z;
    }
    if (id == 0) *gtot = 0;
    if (id < 3 * CH * CH) {
        int w = id / (CH * CH);
        int r = id - w * (CH * CH);
        int k = r / CH;
        int n = r - k * CH;
        const float* Ws = (w == 0) ? W1 : (w == 1) ? W2 : W3;
        float v = Ws[k * CH + n];
        unsigned short h = f2bf(v);
        WH[w * CH * CH + n * CH + k] = h;
        WL[w * CH * CH + n * CH + k] = f2bf(v - bf2f(h));
    }
}

// ---------------- front: gemm-1 (blocks < GBLK) + edge histogram (rest) --------
// R0-proven structure (monolithic 36KB W staging, gemm-first dispatch order).
// R3 lesson: chunked staging serializes W-load latency 3x -> 18us slower. Keep.
__global__ __launch_bounds__(256) void k_front(const float* __restrict__ X,
                                               const unsigned short* __restrict__ WH,
                                               const unsigned short* __restrict__ WL,
                                               unsigned short* __restrict__ H,
                                               const int* __restrict__ dst,
                                               int* __restrict__ cntp,
                                               int* __restrict__ slot) {
    __shared__ __align__(16) unsigned short WsH[CH * CH];  // 18 KB
    __shared__ __align__(16) unsigned short WsL[CH * CH];  // 18 KB

    const int tid = threadIdx.x;

    if (blockIdx.x >= GBLK) {  // ---- histogram path: padded counters ----
        int e = (blockIdx.x - GBLK) * 256 + tid;
        slot[e] = atomicAdd(&cntp[(size_t)dst[e] * 16], 1);
        return;
    }

    // ---- gemm-1 path: H = X(fp32) @ W1, split-bf16 (3 MFMAs) ----
    const int n0 = blockIdx.x * TM;
    {
        const uint4* sH = reinterpret_cast<const uint4*>(WH);
        const uint4* sL = reinterpret_cast<const uint4*>(WL);
        uint4* dH = reinterpret_cast<uint4*>(WsH);
        uint4* dL = reinterpret_cast<uint4*>(WsL);
        for (int i = tid; i < CH * CH / 8; i += 256) {
            dH[i] = sH[i];
            dL[i] = sL[i];
        }
    }
    __syncthreads();

    const int lane = tid & 63;
    const int wave = tid >> 6;
    const int lrow = lane & 15;
    const int quad = lane >> 4;

    const float4* X4 = reinterpret_cast<const float4*>(X);

    f32x4 acc[2][6];
#pragma unroll
    for (int rt = 0; rt < 2; rt++)
#pragma unroll
        for (int ct = 0; ct < 6; ct++) acc[rt][ct] = (f32x4){0.f, 0.f, 0.f, 0.f};

    int arow[2];
#pragma unroll
    for (int rt = 0; rt < 2; rt++)
        arow[rt] = min(n0 + (wave * 2 + rt) * 16 + lrow, NN - 1);

#pragma unroll
    for (int kc = 0; kc < 3; kc++) {
        bf16x8 ahi[2], alo[2];
#pragma unroll
        for (int rt = 0; rt < 2; rt++) {
            int fo = (arow[rt] * CH + kc * 32 + quad * 8) >> 2;
            split8(X4[fo], X4[fo + 1], ahi[rt], alo[rt]);
        }
#pragma unroll
        for (int ct = 0; ct < 6; ct++) {
            int bo = (ct * 16 + lrow) * CH + kc * 32 + quad * 8;
            bf16x8 bhi = *reinterpret_cast<const bf16x8*>(&WsH[bo]);
            bf16x8 blo = *reinterpret_cast<const bf16x8*>(&WsL[bo]);
#pragma unroll
            for (int rt = 0; rt < 2; rt++) {
                acc[rt][ct] = __builtin_amdgcn_mfma_f32_16x16x32_bf16(
                    alo[rt], bhi, acc[rt][ct], 0, 0, 0);
                acc[rt][ct] = __builtin_amdgcn_mfma_f32_16x16x32_bf16(
                    ahi[rt], blo, acc[rt][ct], 0, 0, 0);
                acc[rt][ct] = __builtin_amdgcn_mfma_f32_16x16x32_bf16(
                    ahi[rt], bhi, acc[rt][ct], 0, 0, 0);
            }
        }
    }

#pragma unroll
    for (int rt = 0; rt < 2; rt++) {
        int rbase = n0 + (wave * 2 + rt) * 16 + quad * 4;
#pragma unroll
        for (int ct = 0; ct < 6; ct++) {
            int col = ct * 16 + lrow;
#pragma unroll
            for (int r = 0; r < 4; r++) {
                int row = rbase + r;
                if (row < NN) H[(size_t)row * CH + col] = f2bf(acc[rt][ct][r]);
            }
        }
    }
}

// unordered CSR offsets: wave-scan + ONE atomic per wave (G12) + dinv + goff
// reads padded cnt, emits compact cntc for the aggregates
__global__ __launch_bounds__(256) void k_offsets(const int* __restrict__ cntp,
                                                 int* __restrict__ cntc,
                                                 int* __restrict__ gtot,
                                                 int* __restrict__ off,
                                                 float* __restrict__ dinv,
                                                 const int* __restrict__ batch,
                                                 int* __restrict__ goff) {
    int i = blockIdx.x * 256 + threadIdx.x;
    int lane = threadIdx.x & 63;
    int c = (i < NN) ? cntp[(size_t)i * 16] : 0;

    // 64-lane inclusive scan
    int incl = c;
#pragma unroll
    for (int d = 1; d < 64; d <<= 1) {
        int t = __shfl_up(incl, d);
        if (lane >= d) incl += t;
    }
    int total = __shfl(incl, 63);
    int base = 0;
    if (lane == 63) base = atomicAdd(gtot, total);
    base = __shfl(base, 63);

    if (i >= NN) return;
    cntc[i] = c;
    off[i] = base + incl - c;
    dinv[i] = rsqrtf((float)c + 1.0f);
    int b = batch[i];
    int bp = (i > 0) ? batch[i - 1] : -1;
    for (int g = bp + 1; g <= b; g++) goff[g] = i;
    if (i == NN - 1)
        for (int g = b + 1; g <= NG; g++) goff[g] = NN;
}

__global__ __launch_bounds__(256) void k_build(const int* __restrict__ src,
                                               const int* __restrict__ dst,
                                               const int* __restrict__ off,
                                               const int* __restrict__ slot,
                                               const float* __restrict__ dinv,
                                               float2* __restrict__ packed) {
    int e = blockIdx.x * 256 + threadIdx.x;
    int s = src[e];
    int d = dst[e];
    packed[off[d] + slot[e]] = make_float2(__int_as_float(s), dinv[s] * dinv[d]);
}

// ---------------- MFMA GEMM (layers 2,3): H(bf16) = X(bf16) @ W, LDS-staged W ---
__global__ __launch_bounds__(256) void k_gemm_bf16(const unsigned short* __restrict__ X,
                                                   const unsigned short* __restrict__ WH,
                                                   const unsigned short* __restrict__ WL,
                                                   unsigned short* __restrict__ H) {
    __shared__ __align__(16) unsigned short WsH[CH * CH];
    __shared__ __align__(16) unsigned short WsL[CH * CH];

    const int tid = threadIdx.x;
    const int n0 = blockIdx.x * TM;

    {
        const uint4* sH = reinterpret_cast<const uint4*>(WH);
        const uint4* sL = reinterpret_cast<const uint4*>(WL);
        uint4* dH = reinterpret_cast<uint4*>(WsH);
        uint4* dL = reinterpret_cast<uint4*>(WsL);
        for (int i = tid; i < CH * CH / 8; i += 256) {
            dH[i] = sH[i];
            dL[i] = sL[i];
        }
    }
    __syncthreads();

    const int lane = tid & 63;
    const int wave = tid >> 6;
    const int lrow = lane & 15;
    const int quad = lane >> 4;

    f32x4 acc[2][6];
#pragma unroll
    for (int rt = 0; rt < 2; rt++)
#pragma unroll
        for (int ct = 0; ct < 6; ct++) acc[rt][ct] = (f32x4){0.f, 0.f, 0.f, 0.f};

    int arow[2];
#pragma unroll
    for (int rt = 0; rt < 2; rt++)
        arow[rt] = min(n0 + (wave * 2 + rt) * 16 + lrow, NN - 1);

#pragma unroll
    for (int kc = 0; kc < 3; kc++) {
        bf16x8 ahi[2];
#pragma unroll
        for (int rt = 0; rt < 2; rt++)
            ahi[rt] = *reinterpret_cast<const bf16x8*>(
                &X[(size_t)arow[rt] * CH + kc * 32 + quad * 8]);
#pragma unroll
        for (int ct = 0; ct < 6; ct++) {
            int bo = (ct * 16 + lrow) * CH + kc * 32 + quad * 8;
            bf16x8 bhi = *reinterpret_cast<const bf16x8*>(&WsH[bo]);
            bf16x8 blo = *reinterpret_cast<const bf16x8*>(&WsL[bo]);
#pragma unroll
            for (int rt = 0; rt < 2; rt++) {
                acc[rt][ct] = __builtin_amdgcn_mfma_f32_16x16x32_bf16(
                    ahi[rt], blo, acc[rt][ct], 0, 0, 0);
                acc[rt][ct] = __builtin_amdgcn_mfma_f32_16x16x32_bf16(
                    ahi[rt], bhi, acc[rt][ct], 0, 0, 0);
            }
        }
    }

#pragma unroll
    for (int rt = 0; rt < 2; rt++) {
        int rbase = n0 + (wave * 2 + rt) * 16 + quad * 4;
#pragma unroll
        for (int ct = 0; ct < 6; ct++) {
            int col = ct * 16 + lrow;
#pragma unroll
            for (int r = 0; r < 4; r++) {
                int row = rbase + r;
                if (row < NN) H[(size_t)row * CH + col] = f2bf(acc[rt][ct][r]);
            }
        }
    }
}

// ---------------- per-dst aggregation: 12 threads/node, 4-deep 16 B gathers ------
// (proven depth; deeper/rotated/LDS-fused all measured worse -> MSHR-bound)
template <bool RELU>
__global__ __launch_bounds__(256) void k_aggregate(const int* __restrict__ off,
                                                   const int* __restrict__ cnt,
                                                   const float2* __restrict__ packed,
                                                   const float* __restrict__ dinv,
                                                   const float* __restrict__ bias,
                                                   const unsigned short* __restrict__ H,
                                                   unsigned short* __restrict__ Bout) {
    int idx = blockIdx.x * 256 + threadIdx.x;  // NN*12
    if (idx >= NN * 12) return;
    int n = idx / 12;
    int c8 = idx - n * 12;  // 8 channels per thread
    int e0 = off[n];
    int e1 = e0 + cnt[n];

    const uint4* H8 = reinterpret_cast<const uint4*>(H);

    float a[8];
    {
        float hf[8];
        unpack8(H8[(size_t)n * 12 + c8], hf);
        float di = dinv[n];
        float d2 = di * di;
        const float4* bias4 = reinterpret_cast<const float4*>(bias);
        float4 b0 = bias4[c8 * 2], b1 = bias4[c8 * 2 + 1];
        float bf[8] = {b0.x, b0.y, b0.z, b0.w, b1.x, b1.y, b1.z, b1.w};
#pragma unroll
        for (int j = 0; j < 8; j++) a[j] = hf[j] * d2 + bf[j];
    }

    int e = e0;
    for (; e + 4 <= e1; e += 4) {  // 4 outstanding 16B gathers
        float2 p0 = packed[e + 0];
        float2 p1 = packed[e + 1];
        float2 p2 = packed[e + 2];
        float2 p3 = packed[e + 3];
        uint4 v0 = H8[(size_t)__float_as_int(p0.x) * 12 + c8];
        uint4 v1 = H8[(size_t)__float_as_int(p1.x) * 12 + c8];
        uint4 v2 = H8[(size_t)__float_as_int(p2.x) * 12 + c8];
        uint4 v3 = H8[(size_t)__float_as_int(p3.x) * 12 + c8];
        float f0[8], f1[8], f2[8], f3[8];
        unpack8(v0, f0); unpack8(v1, f1); unpack8(v2, f2); unpack8(v3, f3);
#pragma unroll
        for (int j = 0; j < 8; j++)
            a[j] += f0[j] * p0.y + f1[j] * p1.y + f2[j] * p2.y + f3[j] * p3.y;
    }
    for (; e < e1; e++) {
        float2 pc = packed[e];
        uint4 v = H8[(size_t)__float_as_int(pc.x) * 12 + c8];
        float f[8];
        unpack8(v, f);
#pragma unroll
        for (int j = 0; j < 8; j++) a[j] += f[j] * pc.y;
    }
    if (RELU) {
#pragma unroll
        for (int j = 0; j < 8; j++) a[j] = fmaxf(a[j], 0.0f);
    }
    uint4 o;
    o.x = (unsigned)f2bf(a[0]) | ((unsigned)f2bf(a[1]) << 16);
    o.y = (unsigned)f2bf(a[2]) | ((unsigned)f2bf(a[3]) << 16);
    o.z = (unsigned)f2bf(a[4]) | ((unsigned)f2bf(a[5]) << 16);
    o.w = (unsigned)f2bf(a[6]) | ((unsigned)f2bf(a[7]) << 16);
    reinterpret_cast<uint4*>(Bout)[(size_t)n * 12 + c8] = o;
}

// ---------------- fused pool + final linear (bf16 input) ----------------
__global__ __launch_bounds__(384) void k_pool_linear(const int* __restrict__ goff,
                                                     const unsigned short* __restrict__ B,
                                                     const float* __restrict__ Wlin,
                                                     float* __restrict__ out) {
    __shared__ float4 sh[16][24];
    __shared__ float pooled[CH];
    int g = blockIdx.x;
    int t = threadIdx.x;
    int nl = t / 24;
    int c4 = t - nl * 24;
    int s = goff[g];
    int e = goff[g + 1];

    float4 acc = make_float4(0.f, 0.f, 0.f, 0.f);
    const ushort4* B4 = reinterpret_cast<const ushort4*>(B);
    for (int n = s + nl; n < e; n += 16) {
        float4 v = us4_to_f4(B4[(size_t)n * 24 + c4]);
        acc.x += v.x; acc.y += v.y; acc.z += v.z; acc.w += v.w;
    }
    sh[nl][c4] = acc;
    __syncthreads();

    if (t < 24) {
        float4 r = make_float4(0.f, 0.f, 0.f, 0.f);
#pragma unroll
        for (int j = 0; j < 16; j++) {
            float4 v = sh[j][t];
            r.x += v.x; r.y += v.y; r.z += v.z; r.w += v.w;
        }
        float inv = 1.0f / fmaxf((float)(e - s), 1.0f);
        pooled[t * 4 + 0] = r.x * inv;
        pooled[t * 4 + 1] = r.y * inv;
        pooled[t * 4 + 2] = r.z * inv;
        pooled[t * 4 + 3] = r.w * inv;
    }
    __syncthreads();

    if (t < OC) {
        float a = 0.0f;
#pragma unroll 8
        for (int k = 0; k < CH; k++) a += pooled[k] * Wlin[k * OC + t];
        out[g * OC + t] = a;
    }
}

// ---------------- launch ----------------
extern "C" void kernel_launch(void* const* d_in, const int* in_sizes, int n_in,
                              void* d_out, int out_size, void* d_ws, size_t ws_size,
                              hipStream_t stream) {
    const float* x = (const float*)d_in[0];
    const int* ei = (const int*)d_in[1];
    const int* src = ei;
    const int* dst = ei + NE;
    const int* batch = (const int*)d_in[2];
    const float* W1 = (const float*)d_in[3];
    const float* b1 = (const float*)d_in[4];
    const float* W2 = (const float*)d_in[5];
    const float* b2 = (const float*)d_in[6];
    const float* W3 = (const float*)d_in[7];
    const float* b3 = (const float*)d_in[8];
    const float* Wlin = (const float*)d_in[9];
    float* out = (float*)d_out;

    char* ws = (char*)d_ws;
    unsigned short* Ha = (unsigned short*)ws;  ws += (size_t)NN * CH * 2;  // 19.2 MB
    unsigned short* Hb = (unsigned short*)ws;  ws += (size_t)NN * CH * 2;  // 19.2 MB
    unsigned short* Bb = (unsigned short*)ws;  ws += (size_t)NN * CH * 2;  // 19.2 MB
    float2* packed = (float2*)ws;   ws += (size_t)NE * 8;        // 6.4 MB
    unsigned short* WH = (unsigned short*)ws;  ws += 3 * CH * CH * 2;  // 55 KB
    unsigned short* WL = (unsigned short*)ws;  ws += 3 * CH * CH * 2;
    float* dinv = (float*)ws;       ws += NN * 4;
    int* off = (int*)ws;            ws += NN * 4;
    int* goff = (int*)ws;           ws += 272 * 4;       // NG+1, padded
    int* cntc = (int*)ws;           ws += (NN + 4) * 4;  // compact cnt + gtot slot
    int* gtot = cntc + NN;
    // padded cnt (1 counter / 64B line, 6.4 MB) aliases Hb: Hb dead until gemm-2,
    // cntp last read by k_offsets. slot aliases Bb (dead until agg1; last read k_build).
    int* cntp = (int*)Hb;
    int* slot = (int*)Bb;

    // init (zero padded cnt/gtot + W prep), front (gemm1 || hist), offsets, build
    k_init<<<NBLK, 256, 0, stream>>>(cntp, gtot, W1, W2, W3, WH, WL);
    k_front<<<GBLK + NE / 256, 256, 0, stream>>>(x, WH, WL, Ha, dst, cntp, slot);
    k_offsets<<<NBLK, 256, 0, stream>>>(cntp, cntc, gtot, off, dinv, batch, goff);
    k_build<<<NE / 256, 256, 0, stream>>>(src, dst, off, slot, dinv, packed);

    const int ablk = (NN * 12 + 255) / 256;

    // layer 1 aggregate: Ha -> Bb (relu)
    k_aggregate<true><<<ablk, 256, 0, stream>>>(off, cntc, packed, dinv, b1, Ha, Bb);
    // layer 2: Bb -> Hb -> Bb (relu)
    k_gemm_bf16<<<GBLK, 256, 0, stream>>>(Bb, WH + CH * CH, WL + CH * CH, Hb);
    k_aggregate<true><<<ablk, 256, 0, stream>>>(off, cntc, packed, dinv, b2, Hb, Bb);
    // layer 3: Bb -> Ha -> Bb (no relu)
    k_gemm_bf16<<<GBLK, 256, 0, stream>>>(Bb, WH + 2 * CH * CH, WL + 2 * CH * CH, Ha);
    k_aggregate<false><<<ablk, 256, 0, stream>>>(off, cntc, packed, dinv, b3, Ha, Bb);

    // fused pool + linear
    k_pool_linear<<<NG, 384, 0, stream>>>(goff, Bb, Wlin, out);
}